// Round 2
// baseline (289.732 us; speedup 1.0000x reference)
//
#include <hip/hip_runtime.h>
#include <math.h>

// Problem constants
#define BATCH 256
#define IC    1152   // 32*6*6 input capsule positions
#define DD    8
#define OO    10
#define EE    16
#define BTILE 64     // batches per block (one wave per o, lanes = batch)
#define NBT   4      // BATCH / BTILE
#define NT    640    // OO * BTILE threads per block (10 waves)
#define CHUNK 9      // ijk positions per block
#define NCHUNK 128   // IC / CHUNK  -> 512 blocks = 2 blocks/CU
#define ROUNDS CHUNK // SJ = 1: one ijk per round, u[16] live across barrier

// pass kernel: recompute u_hat on the fly.
//  - W is consumed from SGPRs (o is wave-uniform via readfirstlane -> s_load).
//  - x is double-buffered in LDS (coalesced loader, register prefetch one
//    round ahead) and shared by all 10 o-waves.
//  - SJ=1: only u[16] (+sacc+vreg) live across the barrier -> ~80-90 VGPR,
//    fits 102-reg cap for 2 blocks/CU (20 waves) without spilling.
//  - softmax exchanges exp(logit) through LDS (logits bounded |lg|<~0.1, so
//    no max subtraction); one barrier per round, double-buffered LDS.
__global__ __launch_bounds__(NT, 5) void caps_pass_kernel(
    const float* __restrict__ x,       // [256][1152][8]
    const float* __restrict__ W,       // [1152][10][8][16]
    const float* __restrict__ V,       // [256][10][16] accumulated v
    float* __restrict__ s_part,        // [NCHUNK][256][10][16]
    int first)
{
    __shared__ float x_lds[2][DD][BTILE];   // d-major: conflict-free b32 reads
    __shared__ float elg_lds[2][NT];

    const int tid = threadIdx.x;
    const int o   = tid >> 6;        // wave id 0..9
    const int bl  = tid & 63;
    const int o_u = __builtin_amdgcn_readfirstlane(o);   // wave-uniform o
    const int b   = blockIdx.y * BTILE + bl;
    const int ijk0 = blockIdx.x * CHUNK;

    // per-thread copy of V[b,o,:] (only needed when routing is active)
    float vreg[EE];
    if (!first) {
        const float4* vp = reinterpret_cast<const float4*>(V + ((size_t)b * OO + o) * EE);
        #pragma unroll
        for (int q = 0; q < 4; ++q) {
            float4 t = vp[q];
            vreg[q * 4 + 0] = t.x; vreg[q * 4 + 1] = t.y;
            vreg[q * 4 + 2] = t.z; vreg[q * 4 + 3] = t.w;
        }
    }

    float sacc[EE];
    #pragma unroll
    for (int e = 0; e < EE; ++e) sacc[e] = 0.f;

    // x loader mapping: threads 0..127 each fetch one float4 per round
    const bool loader = tid < BTILE * 2;   // 128
    const int lb = (tid >> 1) & 63;        // batch within tile
    const int lq = tid & 1;                // which half of the 8 d's
    const float* xbase = x + (size_t)(blockIdx.y * BTILE + lb) * (IC * DD) + lq * 4;

    // prologue: load round 0, write to buffer 0
    float4 xpre = make_float4(0.f, 0.f, 0.f, 0.f);
    if (loader) {
        xpre = *reinterpret_cast<const float4*>(xbase + (size_t)ijk0 * DD);
        x_lds[0][lq * 4 + 0][lb] = xpre.x;
        x_lds[0][lq * 4 + 1][lb] = xpre.y;
        x_lds[0][lq * 4 + 2][lb] = xpre.z;
        x_lds[0][lq * 4 + 3][lb] = xpre.w;
    }
    __syncthreads();

    int p = 0;
    for (int r = 0; r < ROUNDS; ++r) {
        // issue global prefetch for round r+1 (latency hidden by compute)
        if (r + 1 < ROUNDS && loader)
            xpre = *reinterpret_cast<const float4*>(
                xbase + (size_t)(ijk0 + r + 1) * DD);

        // compute u for this ijk; write exp(logit)
        const int ijk = ijk0 + r;
        const float* wp = W + (size_t)ijk * (OO * DD * EE) + o_u * (DD * EE);
        float xr[DD];
        #pragma unroll
        for (int d = 0; d < DD; ++d) xr[d] = x_lds[p][d][bl];
        float u[EE];
        #pragma unroll
        for (int e = 0; e < EE; ++e) u[e] = 0.f;
        #pragma unroll
        for (int d = 0; d < DD; ++d) {
            #pragma unroll
            for (int e = 0; e < EE; ++e)
                u[e] = fmaf(xr[d], wp[d * EE + e], u[e]);  // W from SGPR
        }
        float elg = 0.f;
        if (!first) {
            float lg = 0.f;
            #pragma unroll
            for (int e = 0; e < EE; ++e) lg += u[e] * vreg[e];
            // logits bounded: softmax without max-subtraction
            elg = __expf(lg);
            elg_lds[p][tid] = elg;
        }

        // write prefetched x into the other buffer
        if (r + 1 < ROUNDS && loader) {
            x_lds[p ^ 1][lq * 4 + 0][lb] = xpre.x;
            x_lds[p ^ 1][lq * 4 + 1][lb] = xpre.y;
            x_lds[p ^ 1][lq * 4 + 2][lb] = xpre.z;
            x_lds[p ^ 1][lq * 4 + 3][lb] = xpre.w;
        }

        // single barrier per round (covers x swap + elg visibility)
        __syncthreads();

        // softmax over o, accumulate s
        if (!first) {
            float den = 0.f;
            #pragma unroll
            for (int oo = 0; oo < OO; ++oo)
                den += elg_lds[p][oo * 64 + bl];
            float c = __fdividef(elg, den);
            #pragma unroll
            for (int e = 0; e < EE; ++e)
                sacc[e] = fmaf(c, u[e], sacc[e]);
        } else {
            #pragma unroll
            for (int e = 0; e < EE; ++e) sacc[e] += u[e];
        }
        p ^= 1;
    }

    // write partial s for this chunk (first pass: c = 0.1 uniform)
    const float mul = first ? 0.1f : 1.0f;
    float* sp = s_part + (((size_t)blockIdx.x * BATCH + b) * OO + o) * EE;
    #pragma unroll
    for (int q = 0; q < 4; ++q) {
        float4 t;
        t.x = mul * sacc[q * 4 + 0]; t.y = mul * sacc[q * 4 + 1];
        t.z = mul * sacc[q * 4 + 2]; t.w = mul * sacc[q * 4 + 3];
        reinterpret_cast<float4*>(sp)[q] = t;
    }
}

// squash kernel: reduce partial s over chunks, squash, update V (or write out).
// 4 waves/block split the 128-chunk reduction 4-way (32 chunks each), then
// LDS-reduce; wave 0 does the squash + store. 640 blocks keep it BW-bound.
__global__ __launch_bounds__(256) void caps_squash_kernel(
    const float* __restrict__ s_part,  // [NCHUNK][256][10][16]
    float* __restrict__ V,             // [256][10][16]
    float* __restrict__ out,           // [256][10][16]
    int accum, int last)
{
    __shared__ float red[3][64];
    const int lane = threadIdx.x & 63;
    const int w    = threadIdx.x >> 6;
    const int g    = blockIdx.x * 64 + lane;    // < 40960

    const float* sp = s_part + g;
    float s = 0.f;
    #pragma unroll 8
    for (int ch = w * (NCHUNK / 4); ch < (w + 1) * (NCHUNK / 4); ++ch)
        s += sp[(size_t)ch * (BATCH * OO * EE)];

    if (w > 0) red[w - 1][lane] = s;
    __syncthreads();
    if (w == 0) {
        s += red[0][lane] + red[1][lane] + red[2][lane];

        // squared norm over the 16-element e axis (lanes g..g+15 share (b,o))
        float sq = s * s;
        #pragma unroll
        for (int m = 1; m < 16; m <<= 1) sq += __shfl_xor(sq, m, 16);

        float scale = sq / (1.f + sq) / (sqrtf(sq) + 1e-6f);
        float v = scale * s;

        if (last)       out[g] = v;
        else if (accum) V[g]  += v;
        else            V[g]   = v;
    }
}

extern "C" void kernel_launch(void* const* d_in, const int* in_sizes, int n_in,
                              void* d_out, int out_size, void* d_ws, size_t ws_size,
                              hipStream_t stream) {
    const float* x = (const float*)d_in[0];   // [256,32,6,6,8]
    const float* W = (const float*)d_in[1];   // [1,32,6,6,10,8,16]
    float* out = (float*)d_out;               // [256,10,16]

    float* s_part = (float*)d_ws;                                   // NCHUNK*40960 floats
    float* V      = s_part + (size_t)NCHUNK * BATCH * OO * EE;      // 40960 floats

    dim3 grid(NCHUNK, NBT), blk(NT);
    const int sq_blocks = (BATCH * OO * EE) / 64;   // 640

    // iteration 1: b=0 -> c uniform 0.1; v1 -> V
    caps_pass_kernel<<<grid, blk, 0, stream>>>(x, W, V, s_part, 1);
    caps_squash_kernel<<<sq_blocks, 256, 0, stream>>>(s_part, V, out, 0, 0);
    // iteration 2: logits = dot(u_hat, v1); V += v2
    caps_pass_kernel<<<grid, blk, 0, stream>>>(x, W, V, s_part, 0);
    caps_squash_kernel<<<sq_blocks, 256, 0, stream>>>(s_part, V, out, 1, 0);
    // iteration 3 (final): logits = dot(u_hat, v1+v2); output v3
    caps_pass_kernel<<<grid, blk, 0, stream>>>(x, W, V, s_part, 0);
    caps_squash_kernel<<<sq_blocks, 256, 0, stream>>>(s_part, V, out, 0, 1);
}